// Round 3
// baseline (124.949 us; speedup 1.0000x reference)
//
#include <hip/hip_runtime.h>

// Problem constants (fixed by setup_inputs): seg (1,1,2160,3840) int32, S=512.
#define HH 2160
#define WW 3840
#define SS 512
#define NW (SS * SS / 32)   // 8192 u32 words per adjacency bitmask
#define NBMAX 512           // seg_main block count (default / max)

typedef unsigned int uint;
typedef unsigned long long ull;

// ---------------------------------------------------------------------------
// Main pass: one sweep over the image.
//  - adjacency: set bit (s*512+n) in a per-block LDS bitmask for each
//    right/down neighbor n != s; flush with PLAIN coalesced stores to
//    wsBm[block][8192] (no global atomics, no prior memset needed).
//  - centers:   per-block LDS histogram, packed (cnt<<40 | sum_y) u64 atomic
//    + sum_x u32 atomic; flush per-block partials to part.
// part layout: uint part[3][SS][nb]  (plane 0=cnt, 1=sum_x, 2=sum_y)
// Overflow (worst case one block sees all its ~16384 pixels in one segment):
//   cnt <= 16384 < 2^24;  sy <= 16384*2159 ~ 3.5e7 < 2^40;  sx <= 6.3e7 < 2^32.
// ---------------------------------------------------------------------------
__global__ __launch_bounds__(512) void seg_main(
    const int* __restrict__ seg, uint* __restrict__ wsBm,
    uint* __restrict__ part, int nb) {
  __shared__ uint s_bm[NW];      // 32 KB adjacency bitmask
  __shared__ ull  s_pk[SS];      // (cnt << 40) | sum_y
  __shared__ uint s_sx[SS];      // sum_x
  for (int i = threadIdx.x; i < NW; i += blockDim.x) s_bm[i] = 0u;
  for (int i = threadIdx.x; i < SS; i += blockDim.x) { s_pk[i] = 0ULL; s_sx[i] = 0u; }
  __syncthreads();

  const int NC = HH * WW / 4;  // int4 chunks; WW % 4 == 0 so chunks never span rows
  const int stride = gridDim.x * blockDim.x;
  const int4* __restrict__ seg4  = (const int4*)seg;
  const int4* __restrict__ seg4d = (const int4*)(seg + WW);  // same chunk idx -> next row

  for (int c = blockIdx.x * blockDim.x + threadIdx.x; c < NC; c += stride) {
    const int p = c * 4;
    const int y = p / WW;
    const int x = p - y * WW;
    const int4 v = seg4[c];
    // down neighbors (clamped at last row -> self -> no edge)
    const int4 d = (y < HH - 1) ? seg4d[c] : v;
    // right neighbor of element 3 (clamped at last column -> self -> no edge)
    const int nxt = (x < WW - 4) ? seg[p + 4] : v.w;

    // adjacency bits; s != n only, so the diagonal is never set
    if (v.x != v.y) { int i = v.x * SS + v.y; atomicOr(&s_bm[i >> 5], 1u << (i & 31)); }
    if (v.y != v.z) { int i = v.y * SS + v.z; atomicOr(&s_bm[i >> 5], 1u << (i & 31)); }
    if (v.z != v.w) { int i = v.z * SS + v.w; atomicOr(&s_bm[i >> 5], 1u << (i & 31)); }
    if (v.w != nxt) { int i = v.w * SS + nxt; atomicOr(&s_bm[i >> 5], 1u << (i & 31)); }
    if (v.x != d.x) { int i = v.x * SS + d.x; atomicOr(&s_bm[i >> 5], 1u << (i & 31)); }
    if (v.y != d.y) { int i = v.y * SS + d.y; atomicOr(&s_bm[i >> 5], 1u << (i & 31)); }
    if (v.z != d.z) { int i = v.z * SS + d.z; atomicOr(&s_bm[i >> 5], 1u << (i & 31)); }
    if (v.w != d.w) { int i = v.w * SS + d.w; atomicOr(&s_bm[i >> 5], 1u << (i & 31)); }

    // centers accumulation: 2 LDS atomics per pixel
    const ull yp = (1ULL << 40) | (ull)(uint)y;
    atomicAdd(&s_pk[v.x], yp); atomicAdd(&s_sx[v.x], (uint)x);
    atomicAdd(&s_pk[v.y], yp); atomicAdd(&s_sx[v.y], (uint)(x + 1));
    atomicAdd(&s_pk[v.z], yp); atomicAdd(&s_sx[v.z], (uint)(x + 2));
    atomicAdd(&s_pk[v.w], yp); atomicAdd(&s_sx[v.w], (uint)(x + 3));
  }
  __syncthreads();

  // flush bitmask: plain coalesced stores (zeros included -> no memset needed)
  uint* myBm = wsBm + (size_t)blockIdx.x * NW;
  for (int i = threadIdx.x; i < NW; i += blockDim.x) myBm[i] = s_bm[i];

  // flush center partials (transposed layout for coalesced finalize reads)
  for (int i = threadIdx.x; i < SS; i += blockDim.x) {
    const ull pk = s_pk[i];
    part[(0 * SS + i) * nb + blockIdx.x] = (uint)(pk >> 40);
    part[(1 * SS + i) * nb + blockIdx.x] = s_sx[i];
    part[(2 * SS + i) * nb + blockIdx.x] = (uint)(pk & ((1ULL << 40) - 1));
  }
}

// ---------------------------------------------------------------------------
// Fused finalize.
// Blocks 0..511: adjacency. Block g owns 16 words (512 cells). OR-reduce the
//   nb per-block masks (coalesced: lanes 0-15 read consecutive words of one
//   mask, lanes 16-31 the next mask, ...), then expand to float4 stores.
// Blocks 512..519: centers. 64 segments per block, 4 threads per segment,
//   coalesced partial reads + width-4 shuffle reduce + divide.
// ---------------------------------------------------------------------------
__global__ __launch_bounds__(256) void finalize(
    const uint* __restrict__ wsBm, const uint* __restrict__ part, int nb,
    float* __restrict__ adj, float* __restrict__ centers) {
  const int g = blockIdx.x;
  const int t = threadIdx.x;

  if (g < SS) {                       // ---- adjacency OR + expand ----
    const int k  = t & 15;            // word within this block's 16-word chunk
    const int bg = t >> 4;            // 16 mask-groups
    uint acc = 0u;
    const uint* base = wsBm + g * 16 + k;
    for (int b = bg; b < nb; b += 16) acc |= base[(size_t)b * NW];

    __shared__ uint s_red[16][16];    // [bg][k]; addr = t -> conflict-free
    __shared__ uint s_word[16];
    s_red[bg][k] = acc;
    __syncthreads();
    if (t < 16) {
      uint w = 0u;
      #pragma unroll
      for (int i = 0; i < 16; i++) w |= s_red[i][t];
      s_word[t] = w;
    }
    __syncthreads();
    if (t < 128) {                    // 512 cells -> 128 float4 stores
      const int cell = t * 4;
      const uint nib = (s_word[cell >> 5] >> (cell & 31)) & 0xFu;
      float4 q;
      q.x = (nib & 1u) ? 1.0f : 0.0f;
      q.y = (nib & 2u) ? 1.0f : 0.0f;
      q.z = (nib & 4u) ? 1.0f : 0.0f;
      q.w = (nib & 8u) ? 1.0f : 0.0f;
      ((float4*)(adj + g * SS))[t] = q;
    }
  } else {                            // ---- centers reduce ----
    const int s = (g - SS) * 64 + (t >> 2);  // 64 segments per block
    const int q = t & 3;                     // 4 threads per segment
    ull cnt = 0, sx = 0, sy = 0;
    for (int b = q; b < nb; b += 4) {
      cnt += part[(0 * SS + s) * nb + b];
      sx  += part[(1 * SS + s) * nb + b];
      sy  += part[(2 * SS + s) * nb + b];
    }
    cnt += __shfl_down(cnt, 2, 4); cnt += __shfl_down(cnt, 1, 4);
    sx  += __shfl_down(sx,  2, 4); sx  += __shfl_down(sx,  1, 4);
    sy  += __shfl_down(sy,  2, 4); sy  += __shfl_down(sy,  1, 4);
    if (q == 0) {
      const double dc = (double)cnt;
      centers[s * 2 + 0] = (float)((double)sx / dc);  // W-axis mean first (torch permute)
      centers[s * 2 + 1] = (float)((double)sy / dc);
    }
  }
}

extern "C" void kernel_launch(void* const* d_in, const int* in_sizes, int n_in,
                              void* d_out, int out_size, void* d_ws, size_t ws_size,
                              hipStream_t stream) {
  const int* seg = (const int*)d_in[0];  // (1,1,2160,3840) int32
  float* out = (float*)d_out;
  float* adj = out;                       // 512*512
  float* centers = out + SS * SS;         // 512*2

  int nb = NBMAX;
  const size_t per_block = (size_t)(NW + 3 * SS) * sizeof(uint);  // 38 KB / block
  if (ws_size < (size_t)nb * per_block) {
    nb = (int)(ws_size / per_block);
    if (nb > NBMAX) nb = NBMAX;
    if (nb < 1) nb = 1;
  }
  uint* wsBm = (uint*)d_ws;                        // nb * 8192 words (16 MB @ nb=512)
  uint* part = wsBm + (size_t)nb * NW;             // 3*512*nb words

  seg_main<<<nb, 512, 0, stream>>>(seg, wsBm, part, nb);
  finalize<<<SS + 8, 256, 0, stream>>>(wsBm, part, nb, adj, centers);
}